// Round 4
// baseline (901.769 us; speedup 1.0000x reference)
//
#include <hip/hip_runtime.h>
#include <hip/hip_bf16.h>
#include <math.h>

using bf16 = __hip_bfloat16;
using bf162 = __hip_bfloat162;
typedef __attribute__((ext_vector_type(8))) short frag_ab;   // 8 bf16 (4 VGPRs)
typedef __attribute__((ext_vector_type(4))) float frag_cd;   // 4 fp32 acc

typedef const __attribute__((address_space(1))) void* gptr_t;
typedef __attribute__((address_space(3))) void* lptr_t;

#define NUM_HEADS 16
#define KV_GROUPS 4
#define SEQ 2048
#define BATCH 4
#define FDIM 2048
#define DH 128
#define NQKV 3072   // H*DH + G*DH + G*DH

// ---------------- fp32 -> bf16 convert (vec4) ----------------
__global__ __launch_bounds__(256) void cvt_f32_bf16(const float* __restrict__ in,
                                                    bf16* __restrict__ out, int n4) {
  int i = blockIdx.x * 256 + threadIdx.x;
  if (i >= n4) return;
  float4 v = ((const float4*)in)[i];
  bf162 a; a.x = __float2bfloat16(v.x); a.y = __float2bfloat16(v.y);
  bf162 b; b.x = __float2bfloat16(v.z); b.y = __float2bfloat16(v.w);
  ((bf162*)out)[2 * i]     = a;
  ((bf162*)out)[2 * i + 1] = b;
}

// ---------------- transpose + cvt: src fp32 [R][C] -> dst bf16 [C][R] ----------------
__global__ __launch_bounds__(256) void transpose_cvt(const float* __restrict__ src,
                                                     bf16* __restrict__ dst,
                                                     int R, int C) {
  __shared__ float tile[64][65];
  const int ct = blockIdx.x, rt = blockIdx.y;
  const int t = threadIdx.x;
  const int c4 = (t & 15) * 4, r0 = t >> 4;
#pragma unroll
  for (int p = 0; p < 4; p++) {
    int r = r0 + p * 16;
    float4 v = *(const float4*)(src + (size_t)(rt * 64 + r) * C + ct * 64 + c4);
    tile[r][c4] = v.x; tile[r][c4 + 1] = v.y; tile[r][c4 + 2] = v.z; tile[r][c4 + 3] = v.w;
  }
  __syncthreads();
  const int cr = t >> 2, k0 = (t & 3) * 16;
  union { int4 v[2]; bf16 h[16]; } u;
#pragma unroll
  for (int i = 0; i < 16; i++) u.h[i] = __float2bfloat16(tile[k0 + i][cr]);
  bf16* d = dst + (size_t)(ct * 64 + cr) * R + rt * 64 + k0;
  *(int4*)d = u.v[0];
  *(int4*)(d + 8) = u.v[1];
}

// ---------------- bf16 transpose: V [mat][s][128] -> VT [mat][128][s] ----------------
__global__ __launch_bounds__(256) void transpose_v(const bf16* __restrict__ src,
                                                   bf16* __restrict__ dst) {
  __shared__ bf16 tile[64][73];   // pad 73: gather reads conflict-free
  const int dt = blockIdx.x, st = blockIdx.y, mat = blockIdx.z;
  const int t = threadIdx.x;
  const bf16* S = src + ((size_t)mat * SEQ + st * 64) * DH + dt * 64;
  const int r = t >> 3, c8 = (t & 7) * 8;   // r in 0..31
#pragma unroll
  for (int p = 0; p < 2; p++) {
    int row = r + p * 32;
    union { int4 v; bf16 h[8]; } u;
    u.v = *(const int4*)(S + (size_t)row * DH + c8);
#pragma unroll
    for (int i = 0; i < 8; i++) tile[row][c8 + i] = u.h[i];
  }
  __syncthreads();
  const int d0 = t >> 3, s0 = (t & 7) * 8;
#pragma unroll
  for (int p = 0; p < 2; p++) {
    int d = d0 + p * 32;
    union { int4 v; bf16 h[8]; } u;
#pragma unroll
    for (int i = 0; i < 8; i++) u.h[i] = tile[s0 + i][d];
    *(int4*)(dst + ((size_t)mat * DH + dt * 64 + d) * SEQ + st * 64 + s0) = u.v;
  }
}

// ---------------- m97-style bf16 MFMA GEMM: C[M,N] = A[M,K] * BT[N,K]^T ----------------
template <int OUTBF>
__global__ __launch_bounds__(256) void gemm128(const bf16* __restrict__ A,
                                               const bf16* __restrict__ BT,
                                               void* __restrict__ Cout,
                                               const float* __restrict__ bias,
                                               int M, int N, int K) {
  __shared__ bf16 a_lds[128 * 32];
  __shared__ bf16 b_lds[128 * 32];
  const int tid = threadIdx.x;
  const int wave = tid >> 6, lane = tid & 63;
  const int quad = lane >> 4, l16 = lane & 15;
  const int m0 = blockIdx.x * 128, n0 = blockIdx.y * 128;
  const int wm = (wave & 1) * 64, wn = (wave >> 1) * 64;

  frag_cd acc[4][4];
#pragma unroll
  for (int mt = 0; mt < 4; mt++)
#pragma unroll
    for (int nt = 0; nt < 4; nt++) acc[mt][nt] = (frag_cd){0.f, 0.f, 0.f, 0.f};

  const int seg0 = wave * 64 + lane;
  const int seg1 = (4 + wave) * 64 + lane;
  const bf16* aP0 = A  + (size_t)(m0 + (seg0 >> 2)) * K + (seg0 & 3) * 8;
  const bf16* aP1 = A  + (size_t)(m0 + (seg1 >> 2)) * K + (seg1 & 3) * 8;
  const bf16* bP0 = BT + (size_t)(n0 + (seg0 >> 2)) * K + (seg0 & 3) * 8;
  const bf16* bP1 = BT + (size_t)(n0 + (seg1 >> 2)) * K + (seg1 & 3) * 8;
  bf16* aL0 = &a_lds[(size_t)wave * 64 * 8];
  bf16* aL1 = &a_lds[(size_t)(4 + wave) * 64 * 8];
  bf16* bL0 = &b_lds[(size_t)wave * 64 * 8];
  bf16* bL1 = &b_lds[(size_t)(4 + wave) * 64 * 8];

  for (int k0 = 0; k0 < K; k0 += 32) {
    __syncthreads();
    __builtin_amdgcn_global_load_lds((gptr_t)(aP0 + k0), (lptr_t)aL0, 16, 0, 0);
    __builtin_amdgcn_global_load_lds((gptr_t)(aP1 + k0), (lptr_t)aL1, 16, 0, 0);
    __builtin_amdgcn_global_load_lds((gptr_t)(bP0 + k0), (lptr_t)bL0, 16, 0, 0);
    __builtin_amdgcn_global_load_lds((gptr_t)(bP1 + k0), (lptr_t)bL1, 16, 0, 0);
    __syncthreads();

    frag_ab af[4], bfr[4];
#pragma unroll
    for (int mt = 0; mt < 4; mt++)
      af[mt] = *(const frag_ab*)&a_lds[(wm + mt * 16 + l16) * 32 + quad * 8];
#pragma unroll
    for (int nt = 0; nt < 4; nt++)
      bfr[nt] = *(const frag_ab*)&b_lds[(wn + nt * 16 + l16) * 32 + quad * 8];
#pragma unroll
    for (int mt = 0; mt < 4; mt++)
#pragma unroll
      for (int nt = 0; nt < 4; nt++)
        acc[mt][nt] = __builtin_amdgcn_mfma_f32_16x16x32_bf16(af[mt], bfr[nt], acc[mt][nt], 0, 0, 0);
  }

#pragma unroll
  for (int mt = 0; mt < 4; mt++) {
#pragma unroll
    for (int nt = 0; nt < 4; nt++) {
#pragma unroll
      for (int r = 0; r < 4; r++) {
        int row = m0 + wm + mt * 16 + quad * 4 + r;
        int col = n0 + wn + nt * 16 + l16;
        float v = acc[mt][nt][r];
        if (bias) v += bias[col];
        if (OUTBF) ((bf16*)Cout)[(size_t)row * N + col] = __float2bfloat16(v);
        else       ((float*)Cout)[(size_t)row * N + col] = v;
      }
    }
  }
}

// ---------------- bias + RoPE + scale + scatter ----------------
__global__ __launch_bounds__(256) void rope_scatter(const bf16* __restrict__ qkv,
                                                    const float* __restrict__ bq,
                                                    const float* __restrict__ bk,
                                                    const float* __restrict__ bv,
                                                    bf16* __restrict__ Q,
                                                    bf16* __restrict__ K,
                                                    bf16* __restrict__ V) {
  int hrg  = blockIdx.x * 4 + (threadIdx.x >> 6);
  int lane = threadIdx.x & 63;
  int hr  = hrg % 24;
  int row = hrg / 24;
  int b = row >> 11, s = row & 2047;
  int kind, idx;
  if (hr < 16)      { kind = 0; idx = hr; }
  else if (hr < 20) { kind = 1; idx = hr - 16; }
  else              { kind = 2; idx = hr - 20; }
  int colbase = (kind == 0) ? idx * 128 : (kind == 1 ? 2048 + idx * 128 : 2560 + idx * 128);
  const bf16* src = qkv + (size_t)row * NQKV + colbase;
  bf162 xv = *(const bf162*)(src + 2 * lane);
  float a  = __bfloat162float(xv.x);
  float bb = __bfloat162float(xv.y);
  const float* bias = (kind == 0) ? bq : (kind == 1 ? bk : bv);
  a  += bias[idx * 128 + 2 * lane];
  bb += bias[idx * 128 + 2 * lane + 1];
  if (kind != 2 && lane < 32) {
    float freq = powf(10000.f, -(float)lane / 32.f);
    float ang  = (float)s * freq;
    float c = cosf(ang), sn = sinf(ang);
    float na = a * c - bb * sn;
    float nb = bb * c + a * sn;
    a = na; bb = nb;
  }
  if (kind == 0) { a *= 0.08838834764831845f; bb *= 0.08838834764831845f; }
  bf16* dst;
  if (kind == 0)      dst = Q + ((size_t)((b * NUM_HEADS + idx) * SEQ + s)) * DH;
  else if (kind == 1) dst = K + ((size_t)((b * KV_GROUPS + idx) * SEQ + s)) * DH;
  else                dst = V + ((size_t)((b * KV_GROUPS + idx) * SEQ + s)) * DH;
  bf162 ov; ov.x = __float2bfloat16(a); ov.y = __float2bfloat16(bb);
  *(bf162*)(dst + 2 * lane) = ov;
}

// ---------------- MFMA flash attention, 128-row Q tiles ----------------
// Block = 4 waves; wave w owns q-rows [q0+32w, q0+32w+32) (mt=0,1 halves).
// Per 64-key tile: stage K (row-major, pad 136) + V^T (pre-transposed global,
// pad 68) with b128 writes; register-prefetch next tile; S = Q*K^T; online
// softmax; P via wave-private LDS (stride 68, conflict-free); O += P*V.
#define KSTRIDE 136
#define VSTRIDE 68
#define PSTRIDE 68
__global__ __launch_bounds__(256, 2) void attn_mfma(const bf16* __restrict__ Q,
                                                    const bf16* __restrict__ K,
                                                    const bf16* __restrict__ VT,
                                                    bf16* __restrict__ O) {
  __shared__ bf16 k_lds[64 * KSTRIDE];     // [key][dim]
  __shared__ bf16 vt_lds[128 * VSTRIDE];   // [dim][key]
  __shared__ bf16 p_lds[4 * 32 * PSTRIDE]; // per-wave [qrow][key]

  const int tid = threadIdx.x;
  const int wave = tid >> 6, lane = tid & 63;
  const int quad = lane >> 4, l16 = lane & 15;

  const int bh   = blockIdx.x >> 4;
  const int tile = 15 - (blockIdx.x & 15);   // biggest trip counts first
  const int h = bh & 15, b = bh >> 4;
  const int grp = h >> 2;
  const int q0 = tile * 128;

  const bf16* Qbase  = Q  + ((size_t)(b * NUM_HEADS + h) * SEQ + q0 + wave * 32) * DH;
  const bf16* Kbase  = K  + ((size_t)(b * KV_GROUPS + grp) * SEQ) * DH;
  const bf16* VTbase = VT + ((size_t)(b * KV_GROUPS + grp) * DH) * SEQ;
  bf16* p_wave = &p_lds[wave * 32 * PSTRIDE];

  // Q fragments (A-layout), resident for whole kernel: 2 mt x 4 kt
  frag_ab qf[2][4];
#pragma unroll
  for (int mt = 0; mt < 2; mt++)
#pragma unroll
    for (int kt = 0; kt < 4; kt++)
      qf[mt][kt] = *(const frag_ab*)(Qbase + (size_t)(mt * 16 + l16) * DH + kt * 32 + quad * 8);

  frag_cd oacc[2][8];
#pragma unroll
  for (int mt = 0; mt < 2; mt++)
#pragma unroll
    for (int t = 0; t < 8; t++) oacc[mt][t] = (frag_cd){0.f, 0.f, 0.f, 0.f};
  float m4[2][4], l4[2][4];
#pragma unroll
  for (int mt = 0; mt < 2; mt++)
#pragma unroll
    for (int r = 0; r < 4; r++) { m4[mt][r] = -1e30f; l4[mt][r] = 0.f; }

  // staging assignments
  const int kr = tid >> 2, kc = (tid & 3) * 32;   // K: 64 rows x 128 dims
  int4 kreg[4], vreg[4];

  const int nkb = 2 * tile + 2;

  // prefetch tile 0
  {
    const bf16* Kt = Kbase;
#pragma unroll
    for (int it = 0; it < 4; it++)
      kreg[it] = *(const int4*)(Kt + (size_t)kr * DH + kc + it * 8);
#pragma unroll
    for (int it = 0; it < 4; it++) {
      int idx = it * 256 + tid;
      vreg[it] = *(const int4*)(VTbase + (size_t)(idx >> 3) * SEQ + (idx & 7) * 8);
    }
  }

  for (int kb = 0; kb < nkb; kb++) {
    __syncthreads();   // previous iteration's LDS reads done
#pragma unroll
    for (int it = 0; it < 4; it++)
      *(int4*)&k_lds[kr * KSTRIDE + kc + it * 8] = kreg[it];
#pragma unroll
    for (int it = 0; it < 4; it++) {
      int idx = it * 256 + tid;
      *(int4*)&vt_lds[(idx >> 3) * VSTRIDE + (idx & 7) * 8] = vreg[it];
    }
    __syncthreads();

    // prefetch next tile into registers (overlaps with compute below)
    if (kb + 1 < nkb) {
      const bf16* Kt = Kbase + (size_t)(kb + 1) * 64 * DH;
#pragma unroll
      for (int it = 0; it < 4; it++)
        kreg[it] = *(const int4*)(Kt + (size_t)kr * DH + kc + it * 8);
      const bf16* Vt = VTbase + (size_t)(kb + 1) * 64;
#pragma unroll
      for (int it = 0; it < 4; it++) {
        int idx = it * 256 + tid;
        vreg[it] = *(const int4*)(Vt + (size_t)(idx >> 3) * SEQ + (idx & 7) * 8);
      }
    }

    // ---- S = Q * K^T : each kf frag feeds both mt halves ----
    frag_cd sacc[2][4];
#pragma unroll
    for (int mt = 0; mt < 2; mt++)
#pragma unroll
      for (int nt = 0; nt < 4; nt++) sacc[mt][nt] = (frag_cd){0.f, 0.f, 0.f, 0.f};
#pragma unroll
    for (int nt = 0; nt < 4; nt++) {
#pragma unroll
      for (int kt = 0; kt < 4; kt++) {
        frag_ab kf = *(const frag_ab*)&k_lds[(nt * 16 + l16) * KSTRIDE + kt * 32 + quad * 8];
        sacc[0][nt] = __builtin_amdgcn_mfma_f32_16x16x32_bf16(qf[0][kt], kf, sacc[0][nt], 0, 0, 0);
        sacc[1][nt] = __builtin_amdgcn_mfma_f32_16x16x32_bf16(qf[1][kt], kf, sacc[1][nt], 0, 0, 0);
      }
    }
    // ---- causal mask (only possible on the last two tiles) ----
    if (kb >= 2 * tile) {
#pragma unroll
      for (int mt = 0; mt < 2; mt++)
#pragma unroll
        for (int nt = 0; nt < 4; nt++)
#pragma unroll
          for (int r = 0; r < 4; r++) {
            int key = kb * 64 + nt * 16 + l16;
            int qr  = q0 + wave * 32 + mt * 16 + quad * 4 + r;
            if (key > qr) sacc[mt][nt][r] = -1e30f;
          }
    }
    // ---- online softmax + P write ----
#pragma unroll
    for (int mt = 0; mt < 2; mt++) {
#pragma unroll
      for (int r = 0; r < 4; r++) {
        float mx = fmaxf(fmaxf(sacc[mt][0][r], sacc[mt][1][r]),
                         fmaxf(sacc[mt][2][r], sacc[mt][3][r]));
#pragma unroll
        for (int off = 1; off < 16; off <<= 1) mx = fmaxf(mx, __shfl_xor(mx, off));
        float mn = fmaxf(m4[mt][r], mx);
        float alpha = __expf(m4[mt][r] - mn);
        float ps = 0.f;
#pragma unroll
        for (int nt = 0; nt < 4; nt++) {
          float p = __expf(sacc[mt][nt][r] - mn);
          sacc[mt][nt][r] = p;
          ps += p;
        }
#pragma unroll
        for (int off = 1; off < 16; off <<= 1) ps += __shfl_xor(ps, off);
        l4[mt][r] = l4[mt][r] * alpha + ps;
        m4[mt][r] = mn;
#pragma unroll
        for (int t = 0; t < 8; t++) oacc[mt][t][r] *= alpha;
      }
#pragma unroll
      for (int nt = 0; nt < 4; nt++)
#pragma unroll
        for (int r = 0; r < 4; r++)
          p_wave[(mt * 16 + quad * 4 + r) * PSTRIDE + nt * 16 + l16] =
              __float2bfloat16(sacc[mt][nt][r]);
    }
    frag_ab pf[2][2];
#pragma unroll
    for (int mt = 0; mt < 2; mt++)
#pragma unroll
      for (int kt2 = 0; kt2 < 2; kt2++)
        pf[mt][kt2] = *(const frag_ab*)&p_wave[(mt * 16 + l16) * PSTRIDE + kt2 * 32 + quad * 8];
    // ---- O += P * V : each vf frag feeds both mt halves ----
#pragma unroll
    for (int nt2 = 0; nt2 < 8; nt2++) {
#pragma unroll
      for (int kt2 = 0; kt2 < 2; kt2++) {
        frag_ab vf = *(const frag_ab*)&vt_lds[(nt2 * 16 + l16) * VSTRIDE + kt2 * 32 + quad * 8];
        oacc[0][nt2] = __builtin_amdgcn_mfma_f32_16x16x32_bf16(pf[0][kt2], vf, oacc[0][nt2], 0, 0, 0);
        oacc[1][nt2] = __builtin_amdgcn_mfma_f32_16x16x32_bf16(pf[1][kt2], vf, oacc[1][nt2], 0, 0, 0);
      }
    }
  }
  // ---- epilogue ----
#pragma unroll
  for (int mt = 0; mt < 2; mt++) {
    float inv[4];
#pragma unroll
    for (int r = 0; r < 4; r++) inv[r] = 1.f / l4[mt][r];
#pragma unroll
    for (int nt2 = 0; nt2 < 8; nt2++) {
#pragma unroll
      for (int r = 0; r < 4; r++) {
        int qr  = q0 + wave * 32 + mt * 16 + quad * 4 + r;
        int col = h * DH + nt2 * 16 + l16;
        O[(size_t)(b * SEQ + qr) * FDIM + col] = __float2bfloat16(oacc[mt][nt2][r] * inv[r]);
      }
    }
  }
}

extern "C" void kernel_launch(void* const* d_in, const int* in_sizes, int n_in,
                              void* d_out, int out_size, void* d_ws, size_t ws_size,
                              hipStream_t stream) {
  const float* x  = (const float*)d_in[0];
  const float* wq = (const float*)d_in[1];
  const float* bq = (const float*)d_in[2];
  const float* wk = (const float*)d_in[3];
  const float* bk = (const float*)d_in[4];
  const float* wv = (const float*)d_in[5];
  const float* bv = (const float*)d_in[6];
  const float* wo = (const float*)d_in[7];
  const float* bo = (const float*)d_in[8];
  float* out = (float*)d_out;

  char* ws = (char*)d_ws;
  size_t off = 0;
  auto alloc = [&](size_t bytes) {
    void* p = ws + off;
    off += (bytes + 255) & ~(size_t)255;
    return p;
  };
  const size_t MS = (size_t)BATCH * SEQ;          // 8192
  bf16* Xb    = (bf16*)alloc(MS * FDIM * 2);
  bf16* WqkvT = (bf16*)alloc((size_t)NQKV * FDIM * 2);
  bf16* WoT   = (bf16*)alloc((size_t)FDIM * FDIM * 2);
  bf16* QKV   = (bf16*)alloc(MS * NQKV * 2);
  bf16* Qb    = (bf16*)alloc((size_t)BATCH * NUM_HEADS * SEQ * DH * 2);
  bf16* Kb    = (bf16*)alloc((size_t)BATCH * KV_GROUPS * SEQ * DH * 2);
  bf16* Vb    = (bf16*)alloc((size_t)BATCH * KV_GROUPS * SEQ * DH * 2);
  bf16* VTb   = (bf16*)alloc((size_t)BATCH * KV_GROUPS * DH * SEQ * 2);
  bf16* Ob    = (bf16*)alloc(MS * FDIM * 2);

  int n4x = (int)(MS * FDIM / 4);
  cvt_f32_bf16<<<(n4x + 255) / 256, 256, 0, stream>>>(x, Xb, n4x);

  transpose_cvt<<<dim3(2048 / 64, 2048 / 64), 256, 0, stream>>>(wq, WqkvT, 2048, 2048);
  transpose_cvt<<<dim3(512 / 64, 2048 / 64), 256, 0, stream>>>(wk, WqkvT + (size_t)2048 * 2048, 2048, 512);
  transpose_cvt<<<dim3(512 / 64, 2048 / 64), 256, 0, stream>>>(wv, WqkvT + (size_t)2560 * 2048, 2048, 512);
  transpose_cvt<<<dim3(2048 / 64, 2048 / 64), 256, 0, stream>>>(wo, WoT, 2048, 2048);

  dim3 g1(MS / 128, NQKV / 128);
  gemm128<1><<<g1, 256, 0, stream>>>(Xb, WqkvT, QKV, nullptr, (int)MS, NQKV, FDIM);

  rope_scatter<<<(int)(MS * 24 / 4), 256, 0, stream>>>(QKV, bq, bk, bv, Qb, Kb, Vb);

  transpose_v<<<dim3(DH / 64, SEQ / 64, BATCH * KV_GROUPS), 256, 0, stream>>>(Vb, VTb);

  attn_mfma<<<BATCH * NUM_HEADS * (SEQ / 128), 256, 0, stream>>>(Qb, Kb, VTb, Ob);

  dim3 g2(MS / 128, FDIM / 128);
  gemm128<0><<<g2, 256, 0, stream>>>(Ob, WoT, out, bo, (int)MS, FDIM, FDIM);
}